// Round 2
// baseline (328.428 us; speedup 1.0000x reference)
//
#include <hip/hip_runtime.h>

// ---------------------------------------------------------------------------
// Head_87033217286245: Conv1d(1024->64,k=3) + span-softmax extractor + MLP
// Round 2: full-row-resident conv GEMM. Each 4KB bert row is fetched ONCE,
// contiguously (fixes round-1's 128B-per-4KB-stride gather that ran at
// 830 GB/s). A lives in LDS as f16 for the block's whole lifetime.
// ---------------------------------------------------------------------------

typedef _Float16 f16x8 __attribute__((ext_vector_type(8)));
typedef _Float16 f16x4 __attribute__((ext_vector_type(4)));
typedef float    f32x4 __attribute__((ext_vector_type(4)));

#define B_      128
#define L_      512
#define DBERT   1024
#define DPROJ   64
#define NSPANS  3
#define HIDDEN  512
#define KSTEPS  32
#define BM      64
#define AROWS   66            // BM + 2 halo
#define ASTR    1032          // f16 row stride: 2064 B = 516 dw = 4 mod 32 banks -> 2-way (free)

// packed weights: [kb][t][nf][lane][j] f16, = W[o=nf*16+(lane&15)][k=kb*32+(lane>>4)*8+j][t]
__global__ __launch_bounds__(256)
void pack_w_kernel(const float* __restrict__ Wc, _Float16* __restrict__ Bp) {
    int idx = blockIdx.x * 256 + threadIdx.x;
    if (idx >= 32 * 3 * 4 * 64) return;
    int lane = idx & 63;
    int rest = idx >> 6;
    int nf   = rest & 3;
    int r2   = rest >> 2;
    int t    = r2 % 3;
    int kb   = r2 / 3;
    int o     = nf * 16 + (lane & 15);
    int kbase = kb * 32 + ((lane >> 4) << 3);
    f16x8 v;
    #pragma unroll
    for (int j = 0; j < 8; ++j)
        v[j] = (_Float16)Wc[(size_t)o * (DBERT * 3) + (size_t)(kbase + j) * 3 + t];
    *(f16x8*)(Bp + (size_t)idx * 8) = v;
}

// 1024 blocks x 256 threads, 1 block/CU. Wave w: rows (w&1)*32..+32, cols (w>>1)*32..+32.
__global__ __launch_bounds__(256, 1)
void conv_gemm_kernel(const float* __restrict__ X, const _Float16* __restrict__ Bp,
                      const float* __restrict__ cb, const float* __restrict__ aw,
                      const float* __restrict__ ab_p,
                      float* __restrict__ Y, float* __restrict__ Lg) {
    __shared__ __align__(16) _Float16 As[AROWS * ASTR];      // 136,224 B
    __shared__ __align__(16) _Float16 Bs[2][6144];           //  24,576 B
    __shared__ float loglds[2][BM];                          //     512 B

    const int tid  = threadIdx.x;
    const int wv   = tid >> 6;
    const int lane = tid & 63;
    const int m0   = blockIdx.x * BM;
    const int l0   = m0 & (L_ - 1);
    const int g0   = m0 - l0;

    // ---- prologue: stream k-half 0 (rows in order, 1KB-contiguous per wave-chunk)
    // seg s (of 8448 = 66 rows * 128): row = s>>7, off16 = s&127. thread does segs tid+c*256.
    #pragma unroll
    for (int g = 0; g < 5; ++g) {
        const int n = (g == 4) ? 1 : 8;
        float4 v[8];
        #pragma unroll
        for (int i = 0; i < 8; ++i) {
            if (i < n) {
                int s = tid + (g * 8 + i) * 256;
                int r = s >> 7, off = s & 127;
                int l = l0 - 1 + r;
                v[i] = make_float4(0.f, 0.f, 0.f, 0.f);
                if (l >= 0 && l < L_)
                    v[i] = *(const float4*)(X + (size_t)(g0 + l) * DBERT + off * 4);
            }
        }
        #pragma unroll
        for (int i = 0; i < 8; ++i) {
            if (i < n) {
                int s = tid + (g * 8 + i) * 256;
                int r = s >> 7, off = s & 127;
                f16x4 h = {(_Float16)v[i].x, (_Float16)v[i].y,
                           (_Float16)v[i].z, (_Float16)v[i].w};
                *(f16x4*)(&As[r * ASTR + off * 4]) = h;
            }
        }
    }
    // stage B(0)
    {
        const uint4* bsrc = (const uint4*)Bp;
        uint4* bdst = (uint4*)&Bs[0][0];
        #pragma unroll
        for (int it = 0; it < 3; ++it) bdst[tid + it * 256] = bsrc[tid + it * 256];
    }
    __syncthreads();

    const f32x4 vzero = {0.f, 0.f, 0.f, 0.f};
    f32x4 acc[2][2];
    #pragma unroll
    for (int a = 0; a < 2; ++a)
        #pragma unroll
        for (int b = 0; b < 2; ++b) acc[a][b] = vzero;

    const int mrow0 = (wv & 1) * 32;
    const int ch    = wv >> 1;

    #pragma unroll 2
    for (int kb = 0; kb < KSTEPS; ++kb) {
        const int cur = kb & 1, nxt = cur ^ 1;
        const bool haveB = (kb + 1) < KSTEPS;

        // issue B prefetch (L2-hot)
        uint4 vb[3];
        if (haveB) {
            const uint4* bsrc = (const uint4*)(Bp + (size_t)(kb + 1) * 6144);
            #pragma unroll
            for (int it = 0; it < 3; ++it) vb[it] = bsrc[tid + it * 256];
        }
        // issue A k-half-1 loads (steps 0..15; 2 segs/step, +1 at step 0)
        float4 va[3];
        int    sr[3], so[3];
        int na = 0;
        if (kb < 16) {
            na = (kb == 0) ? 3 : 2;
            #pragma unroll
            for (int j = 0; j < 3; ++j) {
                if (j < na) {
                    int c = (j == 2) ? 32 : kb * 2 + j;
                    int s = tid + c * 256;
                    sr[j] = s >> 7; so[j] = s & 127;
                    int l = l0 - 1 + sr[j];
                    va[j] = make_float4(0.f, 0.f, 0.f, 0.f);
                    if (l >= 0 && l < L_)
                        va[j] = *(const float4*)(X + (size_t)(g0 + l) * DBERT + 512 + so[j] * 4);
                }
            }
        }

        // ---- compute step kb
        f16x8 afr[2][3], bfr[2][3];
        #pragma unroll
        for (int mf = 0; mf < 2; ++mf)
            #pragma unroll
            for (int t = 0; t < 3; ++t)
                afr[mf][t] = *(const f16x8*)(
                    &As[(mrow0 + mf * 16 + (lane & 15) + t) * ASTR + kb * 32 + ((lane >> 4) << 3)]);
        #pragma unroll
        for (int nf = 0; nf < 2; ++nf)
            #pragma unroll
            for (int t = 0; t < 3; ++t)
                bfr[nf][t] = *(const f16x8*)(&Bs[cur][(((t * 4 + ch * 2 + nf) * 64) + lane) * 8]);
        #pragma unroll
        for (int mf = 0; mf < 2; ++mf)
            #pragma unroll
            for (int nf = 0; nf < 2; ++nf)
                #pragma unroll
                for (int t = 0; t < 3; ++t)
                    acc[mf][nf] = __builtin_amdgcn_mfma_f32_16x16x32_f16(
                        afr[mf][t], bfr[nf][t], acc[mf][nf], 0, 0, 0);

        // ---- late writes (latency hidden under compute)
        #pragma unroll
        for (int j = 0; j < 3; ++j) {
            if (j < na) {
                f16x4 h = {(_Float16)va[j].x, (_Float16)va[j].y,
                           (_Float16)va[j].z, (_Float16)va[j].w};
                *(f16x4*)(&As[sr[j] * ASTR + 512 + so[j] * 4]) = h;
            }
        }
        if (haveB) {
            uint4* bdst = (uint4*)&Bs[nxt][0];
            #pragma unroll
            for (int it = 0; it < 3; ++it) bdst[tid + it * 256] = vb[it];
        }
        __syncthreads();
    }

    // ---- epilogue: bias+store Y, and per-row logits (dot with att_w)
    if (tid < 2 * BM) ((float*)loglds)[tid] = 0.f;
    __syncthreads();

    const float aw0 = aw[ch * 32 + (lane & 15)];
    const float aw1 = aw[ch * 32 + 16 + (lane & 15)];
    #pragma unroll
    for (int mf = 0; mf < 2; ++mf) {
        #pragma unroll
        for (int nf = 0; nf < 2; ++nf) {
            int col = ch * 32 + nf * 16 + (lane & 15);
            float bias = cb[col];
            #pragma unroll
            for (int i = 0; i < 4; ++i) {
                int row = m0 + mrow0 + mf * 16 + ((lane >> 4) << 2) + i;
                Y[(size_t)row * DPROJ + col] = acc[mf][nf][i] + bias;
            }
        }
        #pragma unroll
        for (int i = 0; i < 4; ++i) {
            float p = acc[mf][0][i] * aw0 + acc[mf][1][i] * aw1;
            p += __shfl_xor(p, 1); p += __shfl_xor(p, 2);
            p += __shfl_xor(p, 4); p += __shfl_xor(p, 8);
            if ((lane & 15) == 0)
                loglds[ch][mrow0 + mf * 16 + ((lane >> 4) << 2) + i] = p;
        }
    }
    __syncthreads();
    if (tid < BM) {
        // logits include conv bias contribution: dot(conv_row, aw) uses biased conv.
        float bdot = 0.f;
        // bias.aw is row-independent: fold it here cheaply per-thread
        // (64 mults; negligible)
        #pragma unroll 16
        for (int c = 0; c < DPROJ; ++c) bdot += cb[c] * aw[c];
        Lg[m0 + tid] = loglds[0][tid] + loglds[1][tid] + bdot + ab_p[0];
    }
}

// One block per batch element.
__global__ __launch_bounds__(256)
void span_mlp_kernel(const float* __restrict__ conv, const float* __restrict__ Lg,
                     const int* __restrict__ offs,
                     const float* __restrict__ in_urls, const float* __restrict__ other,
                     const float* __restrict__ bn1_g, const float* __restrict__ bn1_b,
                     const float* __restrict__ bn1_m, const float* __restrict__ bn1_v,
                     const float* __restrict__ fc_w, const float* __restrict__ fc_b,
                     const float* __restrict__ bn2_g, const float* __restrict__ bn2_b,
                     const float* __restrict__ bn2_m, const float* __restrict__ bn2_v,
                     const float* __restrict__ last_w, const float* __restrict__ last_b,
                     float* __restrict__ out) {
    __shared__ float logits[L_];
    __shared__ float red[8];
    __shared__ float emb[NSPANS * DPROJ];
    __shared__ float hbuf[HIDDEN];

    const int b    = blockIdx.x;
    const int tid  = threadIdx.x;
    const int lane = tid & 63;
    const int wv   = tid >> 6;
    const float* cv = conv + (size_t)b * L_ * DPROJ;

    if (tid < 128) {
        float4 v = *(const float4*)(Lg + (size_t)b * L_ + tid * 4);
        *(float4*)(&logits[tid * 4]) = v;
    }
    __syncthreads();

    for (int sp = 0; sp < NSPANS; ++sp) {
        const int st = offs[b * (NSPANS * 2) + sp * 2 + 0];
        const int en = offs[b * (NSPANS * 2) + sp * 2 + 1];   // inclusive

        float mx = -1e30f;
        for (int l = st + tid; l <= en; l += 256) mx = fmaxf(mx, logits[l]);
        #pragma unroll
        for (int off = 32; off >= 1; off >>= 1) mx = fmaxf(mx, __shfl_xor(mx, off));
        if (lane == 0) red[wv] = mx;
        __syncthreads();
        mx = fmaxf(fmaxf(red[0], red[1]), fmaxf(red[2], red[3]));
        __syncthreads();

        float sm = 0.f;
        for (int l = st + tid; l <= en; l += 256) sm += __expf(logits[l] - mx);
        #pragma unroll
        for (int off = 32; off >= 1; off >>= 1) sm += __shfl_xor(sm, off);
        if (lane == 0) red[wv] = sm;
        __syncthreads();
        const float denom = red[0] + red[1] + red[2] + red[3];

        float a = 0.f;
        for (int l = st + wv; l <= en; l += 4)
            a += __expf(logits[l] - mx) * cv[l * DPROJ + lane];
        hbuf[tid] = a;
        __syncthreads();
        if (tid < DPROJ)
            emb[sp * DPROJ + tid] =
                (hbuf[tid] + hbuf[64 + tid] + hbuf[128 + tid] + hbuf[192 + tid]) / denom;
        __syncthreads();
    }

    for (int i = tid; i < NSPANS * DPROJ; i += 256)
        emb[i] = (emb[i] - bn1_m[i]) * rsqrtf(bn1_v[i] + 1e-5f) * bn1_g[i] + bn1_b[i];
    __syncthreads();

    for (int jj = 0; jj < HIDDEN / 4; ++jj) {
        const int j = wv * (HIDDEN / 4) + jj;
        const float* wrow = fc_w + (size_t)j * (NSPANS * DPROJ);
        float s = wrow[lane] * emb[lane] + wrow[64 + lane] * emb[64 + lane] +
                  wrow[128 + lane] * emb[128 + lane];
        #pragma unroll
        for (int off = 32; off >= 1; off >>= 1) s += __shfl_xor(s, off);
        if (lane == 0) {
            s += fc_b[j];
            s = fmaxf(s, 0.f);
            hbuf[j] = (s - bn2_m[j]) * rsqrtf(bn2_v[j] + 1e-5f) * bn2_g[j] + bn2_b[j];
        }
    }
    __syncthreads();

    if (wv < 3) {
        const float* lw = last_w + wv * (HIDDEN + 17);
        float s = 0.f;
        for (int i = lane; i < HIDDEN + 17; i += 64) {
            float f;
            if (i < HIDDEN)          f = hbuf[i];
            else if (i < HIDDEN + 3) f = in_urls[b * 3 + (i - HIDDEN)];
            else                     f = other[b * 14 + (i - HIDDEN - 3)];
            s += lw[i] * f;
        }
        #pragma unroll
        for (int off = 32; off >= 1; off >>= 1) s += __shfl_xor(s, off);
        if (lane == 0) out[b * 3 + wv] = s + last_b[wv];
    }
}

extern "C" void kernel_launch(void* const* d_in, const int* in_sizes, int n_in,
                              void* d_out, int out_size, void* d_ws, size_t ws_size,
                              hipStream_t stream) {
    const float* bert    = (const float*)d_in[0];
    const int*   offs    = (const int*)d_in[1];
    const float* in_urls = (const float*)d_in[2];
    const float* other   = (const float*)d_in[3];
    const float* conv_w  = (const float*)d_in[4];
    const float* conv_b  = (const float*)d_in[5];
    const float* att_w   = (const float*)d_in[6];
    const float* att_b   = (const float*)d_in[7];
    const float* bn1_g   = (const float*)d_in[8];
    const float* bn1_b   = (const float*)d_in[9];
    const float* bn1_m   = (const float*)d_in[10];
    const float* bn1_v   = (const float*)d_in[11];
    const float* fc_w    = (const float*)d_in[12];
    const float* fc_b    = (const float*)d_in[13];
    const float* bn2_g   = (const float*)d_in[14];
    const float* bn2_b   = (const float*)d_in[15];
    const float* bn2_m   = (const float*)d_in[16];
    const float* bn2_v   = (const float*)d_in[17];
    const float* last_w  = (const float*)d_in[18];
    const float* last_b  = (const float*)d_in[19];

    // ws: [0,393216) packed W f16 | [393216, +16.78MB) conv_out | then logits 256KB
    _Float16* Bp      = (_Float16*)d_ws;
    float*    convout = (float*)((char*)d_ws + 393216);
    float*    logits  = (float*)((char*)d_ws + 393216 + (size_t)B_ * L_ * DPROJ * 4);

    hipLaunchKernelGGL(pack_w_kernel, dim3(96), dim3(256), 0, stream, conv_w, Bp);
    hipLaunchKernelGGL(conv_gemm_kernel, dim3((B_ * L_) / BM), dim3(256), 0, stream,
                       bert, Bp, conv_b, att_w, att_b, convout, logits);
    hipLaunchKernelGGL(span_mlp_kernel, dim3(B_), dim3(256), 0, stream,
                       convout, logits, offs, in_urls, other,
                       bn1_g, bn1_b, bn1_m, bn1_v, fc_w, fc_b,
                       bn2_g, bn2_b, bn2_m, bn2_v, last_w, last_b,
                       (float*)d_out);
}

// Round 3
// 166.670 us; speedup vs baseline: 1.9705x; 1.9705x over previous
//
#include <hip/hip_runtime.h>

// ---------------------------------------------------------------------------
// Head_87033217286245: Conv1d(1024->64,k=3) + span-softmax extractor + MLP
// Round 3: full-row-resident conv GEMM, 8 waves/block (2/SIMD), lag-2 A-drip
// with B-issued-first vmcnt discipline (no exposed HBM latency in loop).
// ---------------------------------------------------------------------------

typedef _Float16 f16x8 __attribute__((ext_vector_type(8)));
typedef _Float16 f16x4 __attribute__((ext_vector_type(4)));
typedef float    f32x4 __attribute__((ext_vector_type(4)));

#define B_      128
#define L_      512
#define DBERT   1024
#define DPROJ   64
#define NSPANS  3
#define HIDDEN  512
#define KSTEPS  32
#define BM      64
#define AROWS   66            // BM + 2 halo
#define ASTR    1032          // f16 row stride (2064 B)

// packed weights: [kb][t][nf][lane][j] f16 = W[o=nf*16+(lane&15)][k=kb*32+(lane>>4)*8+j][t]
__global__ __launch_bounds__(256)
void pack_w_kernel(const float* __restrict__ Wc, _Float16* __restrict__ Bp) {
    int idx = blockIdx.x * 256 + threadIdx.x;
    if (idx >= 32 * 3 * 4 * 64) return;
    int lane = idx & 63;
    int rest = idx >> 6;
    int nf   = rest & 3;
    int r2   = rest >> 2;
    int t    = r2 % 3;
    int kb   = r2 / 3;
    int o     = nf * 16 + (lane & 15);
    int kbase = kb * 32 + ((lane >> 4) << 3);
    f16x8 v;
    #pragma unroll
    for (int j = 0; j < 8; ++j)
        v[j] = (_Float16)Wc[(size_t)o * (DBERT * 3) + (size_t)(kbase + j) * 3 + t];
    *(f16x8*)(Bp + (size_t)idx * 8) = v;
}

// 1024 blocks x 512 threads (8 waves), 1 block/CU (LDS-capped).
// Wave w: rows (w&1)*32..+32, cols (w>>2... see ch) -- ch = w>>1 in [0,4): 16 cols each.
__global__ __launch_bounds__(512, 2)
void conv_gemm_kernel(const float* __restrict__ X, const _Float16* __restrict__ Bp,
                      const float* __restrict__ cb, const float* __restrict__ aw,
                      const float* __restrict__ ab_p,
                      float* __restrict__ Y, float* __restrict__ Lg) {
    __shared__ __align__(16) _Float16 As[AROWS * ASTR];      // 136,224 B
    __shared__ __align__(16) _Float16 Bs[2][6144];           //  24,576 B
    __shared__ float loglds[4][BM];                          //   1,024 B

    const int tid  = threadIdx.x;
    const int wv   = tid >> 6;
    const int lane = tid & 63;
    const int m0   = blockIdx.x * BM;
    const int l0   = m0 & (L_ - 1);
    const int g0   = m0 - l0;

    // ---- prologue: k-half-0 (8448 segs of 16B), deep-issued in 2 batches
    {
        float4 v[9];
        #pragma unroll
        for (int c = 0; c < 8; ++c) {
            int s = tid + c * 512;
            int r = s >> 7, off = s & 127;
            int l = l0 - 1 + r;
            v[c] = make_float4(0.f, 0.f, 0.f, 0.f);
            if (l >= 0 && l < L_)
                v[c] = *(const float4*)(X + (size_t)(g0 + l) * DBERT + off * 4);
        }
        #pragma unroll
        for (int c = 0; c < 8; ++c) {
            int s = tid + c * 512;
            int r = s >> 7, off = s & 127;
            f16x4 h = {(_Float16)v[c].x, (_Float16)v[c].y, (_Float16)v[c].z, (_Float16)v[c].w};
            *(f16x4*)(&As[r * ASTR + off * 4]) = h;
        }
        #pragma unroll
        for (int c = 8; c < 17; ++c) {
            bool act = (c < 16) || (tid < 256);
            int s = tid + c * 512;
            int r = s >> 7, off = s & 127;
            int l = l0 - 1 + r;
            v[c - 8] = make_float4(0.f, 0.f, 0.f, 0.f);
            if (act && l >= 0 && l < L_)
                v[c - 8] = *(const float4*)(X + (size_t)(g0 + l) * DBERT + off * 4);
        }
        #pragma unroll
        for (int c = 8; c < 17; ++c) {
            bool act = (c < 16) || (tid < 256);
            if (act) {
                int s = tid + c * 512;
                int r = s >> 7, off = s & 127;
                f16x4 h = {(_Float16)v[c - 8].x, (_Float16)v[c - 8].y,
                           (_Float16)v[c - 8].z, (_Float16)v[c - 8].w};
                *(f16x4*)(&As[r * ASTR + off * 4]) = h;
            }
        }
        // stage B(0): 768 uint4
        const uint4* bsrc = (const uint4*)Bp;
        uint4* bdst = (uint4*)&Bs[0][0];
        bdst[tid] = bsrc[tid];
        if (tid < 256) bdst[512 + tid] = bsrc[512 + tid];
    }
    __syncthreads();

    const f32x4 vzero = {0.f, 0.f, 0.f, 0.f};
    f32x4 acc[2];
    acc[0] = vzero; acc[1] = vzero;

    const int mrow0 = (wv & 1) * 32;
    const int ch    = wv >> 1;                  // 0..3, 16 cols each

    // drip queue: chunks c of k-half-1 (17 chunks of 512 segs; c==16 half)
    float4 vaq[2][2];

    #pragma unroll 2
    for (int kb = 0; kb < KSTEPS; ++kb) {
        const int p = kb & 1;

        // (a) write drip chunks issued at step kb-2 (loads provably landed)
        if (kb >= 2 && kb <= 10) {
            #pragma unroll
            for (int j = 0; j < 2; ++j) {
                int c = 2 * (kb - 2) + j;
                if (c < 16 || (c == 16 && tid < 256)) {
                    int s = 512 * c + tid;
                    int r = s >> 7, off = s & 127;
                    float4 v = vaq[p][j];
                    f16x4 h = {(_Float16)v.x, (_Float16)v.y, (_Float16)v.z, (_Float16)v.w};
                    *(f16x4*)(&As[r * ASTR + 512 + off * 4]) = h;
                }
            }
        }
        // (b) issue B prefetch FIRST (older in vmcnt order than A-chunks)
        uint4 vb0, vb1;
        const bool haveB = (kb + 1) < KSTEPS;
        if (haveB) {
            const uint4* bsrc = (const uint4*)(Bp + (size_t)(kb + 1) * 6144);
            vb0 = bsrc[tid];
            if (tid < 256) vb1 = bsrc[512 + tid];
        }
        // (c) issue A drip chunks (HBM; stay outstanding across this step)
        if (kb <= 8) {
            #pragma unroll
            for (int j = 0; j < 2; ++j) {
                int c = 2 * kb + j;
                if (c < 16 || (c == 16 && tid < 256)) {
                    int s = 512 * c + tid;
                    int r = s >> 7, off = s & 127;
                    int l = l0 - 1 + r;
                    float4 v = make_float4(0.f, 0.f, 0.f, 0.f);
                    if (l >= 0 && l < L_)
                        v = *(const float4*)(X + (size_t)(g0 + l) * DBERT + 512 + off * 4);
                    vaq[p][j] = v;
                }
            }
        }

        // (d) compute step kb
        f16x8 afr[2][3], bfr[3];
        #pragma unroll
        for (int mf = 0; mf < 2; ++mf)
            #pragma unroll
            for (int t = 0; t < 3; ++t)
                afr[mf][t] = *(const f16x8*)(
                    &As[(mrow0 + mf * 16 + (lane & 15) + t) * ASTR + kb * 32 + ((lane >> 4) << 3)]);
        #pragma unroll
        for (int t = 0; t < 3; ++t)
            bfr[t] = *(const f16x8*)(&Bs[p][(((t * 4 + ch) * 64) + lane) * 8]);
        #pragma unroll
        for (int mf = 0; mf < 2; ++mf)
            #pragma unroll
            for (int t = 0; t < 3; ++t)
                acc[mf] = __builtin_amdgcn_mfma_f32_16x16x32_f16(
                    afr[mf][t], bfr[t], acc[mf], 0, 0, 0);

        // (e) write B (waits only the L2-hot B loads; A-chunks stay in flight)
        if (haveB) {
            uint4* bdst = (uint4*)&Bs[p ^ 1][0];
            bdst[tid] = vb0;
            if (tid < 256) bdst[512 + tid] = vb1;
        }
        __syncthreads();
    }

    // ---- epilogue: bias + store Y; per-row logit partials
    const float awl = aw[ch * 16 + (lane & 15)];
    #pragma unroll
    for (int mf = 0; mf < 2; ++mf) {
        int col = ch * 16 + (lane & 15);
        float bias = cb[col];
        #pragma unroll
        for (int i = 0; i < 4; ++i) {
            int row = m0 + mrow0 + mf * 16 + ((lane >> 4) << 2) + i;
            Y[(size_t)row * DPROJ + col] = acc[mf][i] + bias;
        }
        #pragma unroll
        for (int i = 0; i < 4; ++i) {
            float pl = acc[mf][i] * awl;
            pl += __shfl_xor(pl, 1); pl += __shfl_xor(pl, 2);
            pl += __shfl_xor(pl, 4); pl += __shfl_xor(pl, 8);
            if ((lane & 15) == 0)
                loglds[ch][mrow0 + mf * 16 + ((lane >> 4) << 2) + i] = pl;
        }
    }
    __syncthreads();
    if (tid < BM) {
        float bdot = 0.f;
        #pragma unroll 16
        for (int c = 0; c < DPROJ; ++c) bdot += cb[c] * aw[c];
        Lg[m0 + tid] = loglds[0][tid] + loglds[1][tid] + loglds[2][tid] + loglds[3][tid]
                       + bdot + ab_p[0];
    }
}

// one block per (batch, span): masked softmax over the span + weighted sum
__global__ __launch_bounds__(256)
void span_emb_kernel(const float* __restrict__ conv, const float* __restrict__ Lg,
                     const int* __restrict__ offs, float* __restrict__ emb) {
    __shared__ float logits[L_];
    __shared__ float red[8];
    __shared__ float part[256];

    const int bs   = blockIdx.x;               // 0..383
    const int b    = bs / NSPANS;
    const int sp   = bs - b * NSPANS;
    const int tid  = threadIdx.x;
    const int lane = tid & 63;
    const int wv   = tid >> 6;

    if (tid < 128)
        *(float4*)(&logits[tid * 4]) = *(const float4*)(Lg + (size_t)b * L_ + tid * 4);
    __syncthreads();

    const int st = offs[b * (NSPANS * 2) + sp * 2 + 0];
    const int en = offs[b * (NSPANS * 2) + sp * 2 + 1];      // inclusive

    float mx = -1e30f;
    for (int l = st + tid; l <= en; l += 256) mx = fmaxf(mx, logits[l]);
    #pragma unroll
    for (int off = 32; off >= 1; off >>= 1) mx = fmaxf(mx, __shfl_xor(mx, off));
    if (lane == 0) red[wv] = mx;
    __syncthreads();
    mx = fmaxf(fmaxf(red[0], red[1]), fmaxf(red[2], red[3]));
    __syncthreads();

    float sm = 0.f;
    for (int l = st + tid; l <= en; l += 256) sm += __expf(logits[l] - mx);
    #pragma unroll
    for (int off = 32; off >= 1; off >>= 1) sm += __shfl_xor(sm, off);
    if (lane == 0) red[wv] = sm;
    __syncthreads();
    const float denom = red[0] + red[1] + red[2] + red[3];

    float a = 0.f;
    for (int l = st + wv; l <= en; l += 4)
        a += __expf(logits[l] - mx) * conv[((size_t)b * L_ + l) * DPROJ + lane];
    part[tid] = a;
    __syncthreads();
    if (tid < DPROJ)
        emb[(size_t)bs * DPROJ + tid] =
            (part[tid] + part[64 + tid] + part[128 + tid] + part[192 + tid]) / denom;
}

// one block per batch: BN1 -> fc(192->512) -> ReLU -> BN2 -> concat -> last(529->3)
__global__ __launch_bounds__(256)
void span_fc_kernel(const float* __restrict__ emb_in,
                    const float* __restrict__ in_urls, const float* __restrict__ other,
                    const float* __restrict__ bn1_g, const float* __restrict__ bn1_b,
                    const float* __restrict__ bn1_m, const float* __restrict__ bn1_v,
                    const float* __restrict__ fc_w, const float* __restrict__ fc_b,
                    const float* __restrict__ bn2_g, const float* __restrict__ bn2_b,
                    const float* __restrict__ bn2_m, const float* __restrict__ bn2_v,
                    const float* __restrict__ last_w, const float* __restrict__ last_b,
                    float* __restrict__ out) {
    __shared__ float emb[NSPANS * DPROJ];
    __shared__ float hbuf[HIDDEN];

    const int b    = blockIdx.x;
    const int tid  = threadIdx.x;
    const int lane = tid & 63;
    const int wv   = tid >> 6;

    if (tid < NSPANS * DPROJ) {
        float e = emb_in[(size_t)b * (NSPANS * DPROJ) + tid];
        emb[tid] = (e - bn1_m[tid]) * rsqrtf(bn1_v[tid] + 1e-5f) * bn1_g[tid] + bn1_b[tid];
    }
    __syncthreads();

    // fc: thread-per-output, 2 outputs each; emb reads are LDS broadcasts
    #pragma unroll
    for (int q = 0; q < 2; ++q) {
        const int j = tid + q * 256;
        const float* wrow = fc_w + (size_t)j * (NSPANS * DPROJ);
        float s = fc_b[j];
        #pragma unroll 8
        for (int i = 0; i < NSPANS * DPROJ; ++i) s += wrow[i] * emb[i];
        s = fmaxf(s, 0.f);
        hbuf[j] = (s - bn2_m[j]) * rsqrtf(bn2_v[j] + 1e-5f) * bn2_g[j] + bn2_b[j];
    }
    __syncthreads();

    if (wv < 3) {
        const float* lw = last_w + wv * (HIDDEN + 17);
        float s = 0.f;
        for (int i = lane; i < HIDDEN + 17; i += 64) {
            float f;
            if (i < HIDDEN)          f = hbuf[i];
            else if (i < HIDDEN + 3) f = in_urls[b * 3 + (i - HIDDEN)];
            else                     f = other[b * 14 + (i - HIDDEN - 3)];
            s += lw[i] * f;
        }
        #pragma unroll
        for (int off = 32; off >= 1; off >>= 1) s += __shfl_xor(s, off);
        if (lane == 0) out[b * 3 + wv] = s + last_b[wv];
    }
}

extern "C" void kernel_launch(void* const* d_in, const int* in_sizes, int n_in,
                              void* d_out, int out_size, void* d_ws, size_t ws_size,
                              hipStream_t stream) {
    const float* bert    = (const float*)d_in[0];
    const int*   offs    = (const int*)d_in[1];
    const float* in_urls = (const float*)d_in[2];
    const float* other   = (const float*)d_in[3];
    const float* conv_w  = (const float*)d_in[4];
    const float* conv_b  = (const float*)d_in[5];
    const float* att_w   = (const float*)d_in[6];
    const float* att_b   = (const float*)d_in[7];
    const float* bn1_g   = (const float*)d_in[8];
    const float* bn1_b   = (const float*)d_in[9];
    const float* bn1_m   = (const float*)d_in[10];
    const float* bn1_v   = (const float*)d_in[11];
    const float* fc_w    = (const float*)d_in[12];
    const float* fc_b    = (const float*)d_in[13];
    const float* bn2_g   = (const float*)d_in[14];
    const float* bn2_b   = (const float*)d_in[15];
    const float* bn2_m   = (const float*)d_in[16];
    const float* bn2_v   = (const float*)d_in[17];
    const float* last_w  = (const float*)d_in[18];
    const float* last_b  = (const float*)d_in[19];

    // ws: Bp 393216 | convout 16.78MB | Lg 256KB | emb 96KB
    _Float16* Bp      = (_Float16*)d_ws;
    float*    convout = (float*)((char*)d_ws + 393216);
    float*    logits  = (float*)((char*)d_ws + 393216 + (size_t)B_ * L_ * DPROJ * 4);
    float*    emb     = (float*)((char*)d_ws + 393216 + (size_t)B_ * L_ * DPROJ * 4 + 262144);

    hipLaunchKernelGGL(pack_w_kernel, dim3(96), dim3(256), 0, stream, conv_w, Bp);
    hipLaunchKernelGGL(conv_gemm_kernel, dim3((B_ * L_) / BM), dim3(512), 0, stream,
                       bert, Bp, conv_b, att_w, att_b, convout, logits);
    hipLaunchKernelGGL(span_emb_kernel, dim3(B_ * NSPANS), dim3(256), 0, stream,
                       convout, logits, offs, emb);
    hipLaunchKernelGGL(span_fc_kernel, dim3(B_), dim3(256), 0, stream,
                       emb, in_urls, other,
                       bn1_g, bn1_b, bn1_m, bn1_v, fc_w, fc_b,
                       bn2_g, bn2_b, bn2_m, bn2_v, last_w, last_b,
                       (float*)d_out);
}

// Round 4
// 152.064 us; speedup vs baseline: 2.1598x; 1.0961x over previous
//
#include <hip/hip_runtime.h>

// ---------------------------------------------------------------------------
// Head_87033217286245: Conv1d(1024->64,k=3) + span-softmax extractor + MLP
// Round 4: BM=32 tiles, A-only LDS (70KB) -> 2 blocks/CU; B direct from L1/L2
// to registers; barrier-free K-loop; 32x32x16 MFMA with ks-split epilogue sum.
// ---------------------------------------------------------------------------

typedef _Float16 f16x8 __attribute__((ext_vector_type(8)));
typedef _Float16 f16x4 __attribute__((ext_vector_type(4)));
typedef float    f32x16 __attribute__((ext_vector_type(16)));

#define B_      128
#define L_      512
#define DBERT   1024
#define DPROJ   64
#define NSPANS  3
#define HIDDEN  512
#define KSTEPS  32
#define BM      32
#define AROWS   34            // BM + 2 halo
#define ASTR    1032          // f16 row stride (2064 B = 129 quads -> rows spread)

// packed weights, 32x32x16 B-frag layout:
// frag f = ((kb*3 + t)*2 + ks)*2 + ch ; lane l ; j=0..7
// Bp[f*512 + l*8 + j] = W[o = ch*32 + (l&31)][k = kb*32 + ks*16 + (l>>5)*8 + j][t]
__global__ __launch_bounds__(256)
void pack_w_kernel(const float* __restrict__ Wc, _Float16* __restrict__ Bp) {
    int idx = blockIdx.x * 256 + threadIdx.x;          // 24576
    if (idx >= 384 * 64) return;
    int lane = idx & 63;
    int f    = idx >> 6;
    int ch   = f & 1;
    int ks   = (f >> 1) & 1;
    int t    = (f >> 2) % 3;
    int kb   = (f >> 2) / 3;
    int o     = ch * 32 + (lane & 31);
    int kbase = kb * 32 + ks * 16 + ((lane >> 5) << 3);
    f16x8 v;
    #pragma unroll
    for (int j = 0; j < 8; ++j)
        v[j] = (_Float16)Wc[(size_t)o * (DBERT * 3) + (size_t)(kbase + j) * 3 + t];
    *(f16x8*)(Bp + (size_t)idx * 8) = v;
}

// 2048 blocks x 256 threads (4 waves), 2 blocks/CU. Wave = (ks = wv>>1, ch = wv&1):
// 32 rows x 32 cols, k-slice half ks. No barriers in the K-loop.
__global__ __launch_bounds__(256, 2)
void conv_gemm_kernel(const float* __restrict__ X, const _Float16* __restrict__ Bp,
                      const float* __restrict__ cb, const float* __restrict__ aw,
                      const float* __restrict__ ab_p,
                      float* __restrict__ Y, float* __restrict__ Lg) {
    __shared__ __align__(16) char shraw[AROWS * ASTR * 2];   // 70,176 B (As, then reduce)
    __shared__ float loglds[2][BM];

    _Float16* As = (_Float16*)shraw;

    const int tid  = threadIdx.x;
    const int wv   = tid >> 6;
    const int lane = tid & 63;
    const int ch   = wv & 1;
    const int ks   = wv >> 1;
    const int m0   = blockIdx.x * BM;
    const int l0   = m0 & (L_ - 1);
    const int g0   = m0 - l0;

    // issue first B frags early (deep in vmem queue)
    f16x8 bcur[3], bnxt[3];
    #pragma unroll
    for (int t = 0; t < 3; ++t)
        bcur[t] = *(const f16x8*)(Bp + ((size_t)((t * 2 + ks) * 2 + ch) * 64 + lane) * 8);

    // ---- prologue: 34 rows, thread covers (row c, 16B col chunk at tid*4 floats)
    #pragma unroll
    for (int base = 0; base < 34; base += 8) {
        const int n = (base + 8 <= 34) ? 8 : (34 - base);
        float4 v[8];
        #pragma unroll
        for (int i = 0; i < 8; ++i) {
            if (i < n) {
                int l = l0 - 1 + base + i;
                v[i] = make_float4(0.f, 0.f, 0.f, 0.f);
                if (l >= 0 && l < L_)
                    v[i] = *(const float4*)(X + (size_t)(g0 + l) * DBERT + tid * 4);
            }
        }
        #pragma unroll
        for (int i = 0; i < 8; ++i) {
            if (i < n) {
                f16x4 h = {(_Float16)v[i].x, (_Float16)v[i].y,
                           (_Float16)v[i].z, (_Float16)v[i].w};
                *(f16x4*)(&As[(base + i) * ASTR + tid * 4]) = h;
            }
        }
    }
    __syncthreads();

    // ---- barrier-free K-loop
    f32x16 acc = {};
    #pragma unroll 2
    for (int kb = 0; kb < KSTEPS; ++kb) {
        if (kb + 1 < KSTEPS) {
            #pragma unroll
            for (int t = 0; t < 3; ++t)
                bnxt[t] = *(const f16x8*)(
                    Bp + ((size_t)((((kb + 1) * 3 + t) * 2 + ks) * 2 + ch) * 64 + lane) * 8);
        }
        f16x8 afr[3];
        const int kboff = kb * 32 + ks * 16 + ((lane >> 5) << 3);
        #pragma unroll
        for (int t = 0; t < 3; ++t)
            afr[t] = *(const f16x8*)(&As[((lane & 31) + t) * ASTR + kboff]);
        #pragma unroll
        for (int t = 0; t < 3; ++t)
            acc = __builtin_amdgcn_mfma_f32_32x32x16_f16(afr[t], bcur[t], acc, 0, 0, 0);
        #pragma unroll
        for (int t = 0; t < 3; ++t) bcur[t] = bnxt[t];
    }

    // ---- epilogue: ks-partial reduce via LDS overlay, then store + logits
    __syncthreads();                    // all As reads done; overlay safe
    float* red = (float*)shraw;         // [ch][lane][16] = 8 KB
    if (ks == 1) {
        #pragma unroll
        for (int i = 0; i < 16; ++i) red[(ch * 64 + lane) * 16 + i] = acc[i];
    }
    __syncthreads();
    if (ks == 0) {
        const int col = ch * 32 + (lane & 31);
        const float cbv = cb[col];
        const float awv = aw[col];
        const int rbase = (lane >> 5) << 2;
        #pragma unroll
        for (int i = 0; i < 16; ++i) {
            float c = acc[i] + red[(ch * 64 + lane) * 16 + i] + cbv;
            int row = (i & 3) + 8 * (i >> 2) + rbase;    // C layout (m74/m101)
            Y[(size_t)(m0 + row) * DPROJ + col] = c;
            float p = c * awv;
            p += __shfl_xor(p, 1);  p += __shfl_xor(p, 2);
            p += __shfl_xor(p, 4);  p += __shfl_xor(p, 8);
            p += __shfl_xor(p, 16);
            if ((lane & 31) == 0) loglds[ch][row] = p;
        }
    }
    __syncthreads();
    if (tid < BM)
        Lg[m0 + tid] = loglds[0][tid] + loglds[1][tid] + ab_p[0];
}

// one block per (batch, span): masked softmax over the span + weighted sum
__global__ __launch_bounds__(256)
void span_emb_kernel(const float* __restrict__ conv, const float* __restrict__ Lg,
                     const int* __restrict__ offs, float* __restrict__ emb) {
    __shared__ float logits[L_];
    __shared__ float red[8];
    __shared__ float part[256];

    const int bs   = blockIdx.x;               // 0..383
    const int b    = bs / NSPANS;
    const int sp   = bs - b * NSPANS;
    const int tid  = threadIdx.x;
    const int lane = tid & 63;
    const int wv   = tid >> 6;

    if (tid < 128)
        *(float4*)(&logits[tid * 4]) = *(const float4*)(Lg + (size_t)b * L_ + tid * 4);
    __syncthreads();

    const int st = offs[b * (NSPANS * 2) + sp * 2 + 0];
    const int en = offs[b * (NSPANS * 2) + sp * 2 + 1];      // inclusive

    float mx = -1e30f;
    for (int l = st + tid; l <= en; l += 256) mx = fmaxf(mx, logits[l]);
    #pragma unroll
    for (int off = 32; off >= 1; off >>= 1) mx = fmaxf(mx, __shfl_xor(mx, off));
    if (lane == 0) red[wv] = mx;
    __syncthreads();
    mx = fmaxf(fmaxf(red[0], red[1]), fmaxf(red[2], red[3]));
    __syncthreads();

    float sm = 0.f;
    for (int l = st + tid; l <= en; l += 256) sm += __expf(logits[l] - mx);
    #pragma unroll
    for (int off = 32; off >= 1; off >>= 1) sm += __shfl_xor(sm, off);
    if (lane == 0) red[wv] = sm;
    __syncthreads();
    const float denom = red[0] + red[1] + red[2] + red[3];

    float a = 0.f;
    for (int l = st + wv; l <= en; l += 4)
        a += __expf(logits[l] - mx) * conv[((size_t)b * L_ + l) * DPROJ + lane];
    part[tid] = a;
    __syncthreads();
    if (tid < DPROJ)
        emb[(size_t)bs * DPROJ + tid] =
            (part[tid] + part[64 + tid] + part[128 + tid] + part[192 + tid]) / denom;
}

// one block per batch: BN1 -> fc(192->512) -> ReLU -> BN2 -> concat -> last(529->3)
__global__ __launch_bounds__(256)
void span_fc_kernel(const float* __restrict__ emb_in,
                    const float* __restrict__ in_urls, const float* __restrict__ other,
                    const float* __restrict__ bn1_g, const float* __restrict__ bn1_b,
                    const float* __restrict__ bn1_m, const float* __restrict__ bn1_v,
                    const float* __restrict__ fc_w, const float* __restrict__ fc_b,
                    const float* __restrict__ bn2_g, const float* __restrict__ bn2_b,
                    const float* __restrict__ bn2_m, const float* __restrict__ bn2_v,
                    const float* __restrict__ last_w, const float* __restrict__ last_b,
                    float* __restrict__ out) {
    __shared__ float emb[NSPANS * DPROJ];
    __shared__ float hbuf[HIDDEN];

    const int b    = blockIdx.x;
    const int tid  = threadIdx.x;
    const int lane = tid & 63;
    const int wv   = tid >> 6;

    if (tid < NSPANS * DPROJ) {
        float e = emb_in[(size_t)b * (NSPANS * DPROJ) + tid];
        emb[tid] = (e - bn1_m[tid]) * rsqrtf(bn1_v[tid] + 1e-5f) * bn1_g[tid] + bn1_b[tid];
    }
    __syncthreads();

    #pragma unroll
    for (int q = 0; q < 2; ++q) {
        const int j = tid + q * 256;
        const float* wrow = fc_w + (size_t)j * (NSPANS * DPROJ);
        float s = fc_b[j];
        #pragma unroll 8
        for (int i = 0; i < NSPANS * DPROJ; ++i) s += wrow[i] * emb[i];
        s = fmaxf(s, 0.f);
        hbuf[j] = (s - bn2_m[j]) * rsqrtf(bn2_v[j] + 1e-5f) * bn2_g[j] + bn2_b[j];
    }
    __syncthreads();

    if (wv < 3) {
        const float* lw = last_w + wv * (HIDDEN + 17);
        float s = 0.f;
        for (int i = lane; i < HIDDEN + 17; i += 64) {
            float f;
            if (i < HIDDEN)          f = hbuf[i];
            else if (i < HIDDEN + 3) f = in_urls[b * 3 + (i - HIDDEN)];
            else                     f = other[b * 14 + (i - HIDDEN - 3)];
            s += lw[i] * f;
        }
        #pragma unroll
        for (int off = 32; off >= 1; off >>= 1) s += __shfl_xor(s, off);
        if (lane == 0) out[b * 3 + wv] = s + last_b[wv];
    }
}

extern "C" void kernel_launch(void* const* d_in, const int* in_sizes, int n_in,
                              void* d_out, int out_size, void* d_ws, size_t ws_size,
                              hipStream_t stream) {
    const float* bert    = (const float*)d_in[0];
    const int*   offs    = (const int*)d_in[1];
    const float* in_urls = (const float*)d_in[2];
    const float* other   = (const float*)d_in[3];
    const float* conv_w  = (const float*)d_in[4];
    const float* conv_b  = (const float*)d_in[5];
    const float* att_w   = (const float*)d_in[6];
    const float* att_b   = (const float*)d_in[7];
    const float* bn1_g   = (const float*)d_in[8];
    const float* bn1_b   = (const float*)d_in[9];
    const float* bn1_m   = (const float*)d_in[10];
    const float* bn1_v   = (const float*)d_in[11];
    const float* fc_w    = (const float*)d_in[12];
    const float* fc_b    = (const float*)d_in[13];
    const float* bn2_g   = (const float*)d_in[14];
    const float* bn2_b   = (const float*)d_in[15];
    const float* bn2_m   = (const float*)d_in[16];
    const float* bn2_v   = (const float*)d_in[17];
    const float* last_w  = (const float*)d_in[18];
    const float* last_b  = (const float*)d_in[19];

    // ws: Bp 384KB | convout 16.78MB | Lg 256KB | emb 96KB
    _Float16* Bp      = (_Float16*)d_ws;
    float*    convout = (float*)((char*)d_ws + 393216);
    float*    logits  = (float*)((char*)d_ws + 393216 + (size_t)B_ * L_ * DPROJ * 4);
    float*    emb     = (float*)((char*)d_ws + 393216 + (size_t)B_ * L_ * DPROJ * 4 + 262144);

    hipLaunchKernelGGL(pack_w_kernel, dim3(96), dim3(256), 0, stream, conv_w, Bp);
    hipLaunchKernelGGL(conv_gemm_kernel, dim3((B_ * L_) / BM), dim3(256), 0, stream,
                       bert, Bp, conv_b, att_w, att_b, convout, logits);
    hipLaunchKernelGGL(span_emb_kernel, dim3(B_ * NSPANS), dim3(256), 0, stream,
                       convout, logits, offs, emb);
    hipLaunchKernelGGL(span_fc_kernel, dim3(B_), dim3(256), 0, stream,
                       emb, in_urls, other,
                       bn1_g, bn1_b, bn1_m, bn1_v, fc_w, fc_b,
                       bn2_g, bn2_b, bn2_m, bn2_v, last_w, last_b,
                       (float*)d_out);
}